// Round 6
// baseline (218.124 us; speedup 1.0000x reference)
//
#include <hip/hip_runtime.h>
#include <hip/hip_bf16.h>

// Problem constants (fixed shapes): B=2, F=32, C=4, D=64, H=128, W=128
#define S_VOX  1048576          // D*H*W = 2^20
#define NVOX   2097152          // B * S_VOX
#define NCLS   4
#define NFEAT  32
#define FEAT_ELEMS 67108864     // B*F*S_VOX
#define EPS_F  1e-8f
#define LOG2_F 0.6931471805599453f

typedef float f32x4 __attribute__((ext_vector_type(4)));

// ---- monotonic float <-> orderable uint key ----
__device__ __forceinline__ unsigned f2key(float f) {
    unsigned u = __float_as_uint(f);
    return (u & 0x80000000u) ? ~u : (u | 0x80000000u);
}
__device__ __forceinline__ float key2f(unsigned k) {
    unsigned u = (k & 0x80000000u) ? (k & 0x7FFFFFFFu) : ~k;
    return __uint_as_float(u);
}

// ws layout (bytes):
//   0   : unsigned mink[4]
//   16  : unsigned maxk[4]
//   32  : int      i64flag
//   64  : float    params[8]   (base[4], mult[4])
//   256 : float    dis[NVOX]

__global__ void k_prolog(const unsigned* __restrict__ lab32,
                         unsigned* __restrict__ mink, unsigned* __restrict__ maxk,
                         int* __restrict__ flag) {
    int t = threadIdx.x;            // 64 threads
    if (t < NCLS) { mink[t] = 0xFFFFFFFFu; maxk[t] = 0u; }
    unsigned even = lab32[2 * t];
    unsigned odd  = lab32[2 * t + 1];
    unsigned long long oddnz  = __ballot(odd  != 0u);
    unsigned long long evennz = __ballot(even != 0u);
    if (t == 0) *flag = (oddnz == 0ull && evennz != 0ull) ? 1 : 0;
}

__global__ void __launch_bounds__(256)
k_dis(const float* __restrict__ lA, const float* __restrict__ lB,
      const unsigned* __restrict__ lab32, const int* __restrict__ i64flag,
      float* __restrict__ dis,
      unsigned* __restrict__ mink, unsigned* __restrict__ maxk) {
    __shared__ unsigned smin[NCLS], smax[NCLS];
    if (threadIdx.x < NCLS) { smin[threadIdx.x] = 0xFFFFFFFFu; smax[threadIdx.x] = 0u; }
    __syncthreads();

    const int lstride = 1 + *i64flag;   // 1 if int32, 2 if int64 (low word)
    unsigned lmin[NCLS] = {0xFFFFFFFFu, 0xFFFFFFFFu, 0xFFFFFFFFu, 0xFFFFFFFFu};
    unsigned lmax[NCLS] = {0u, 0u, 0u, 0u};

    const int nquad = NVOX / 4;
    for (int q = blockIdx.x * blockDim.x + threadIdx.x; q < nquad;
         q += gridDim.x * blockDim.x) {
        const int g = q << 2;                 // base voxel index
        const int b = g >> 20;                // batch
        const int v = g & (S_VOX - 1);
        const size_t abase = ((size_t)b * NCLS) * S_VOX + v;

        float4 a0 = *(const float4*)(lA + abase);
        float4 a1 = *(const float4*)(lA + abase + S_VOX);
        float4 a2 = *(const float4*)(lA + abase + 2 * (size_t)S_VOX);
        float4 a3 = *(const float4*)(lA + abase + 3 * (size_t)S_VOX);
        float4 c0 = *(const float4*)(lB + abase);
        float4 c1 = *(const float4*)(lB + abase + S_VOX);
        float4 c2 = *(const float4*)(lB + abase + 2 * (size_t)S_VOX);
        float4 c3 = *(const float4*)(lB + abase + 3 * (size_t)S_VOX);

        float dv[4];
        #pragma unroll
        for (int j = 0; j < 4; ++j) {
            float av[NCLS] = { ((const float*)&a0)[j], ((const float*)&a1)[j],
                               ((const float*)&a2)[j], ((const float*)&a3)[j] };
            float bv[NCLS] = { ((const float*)&c0)[j], ((const float*)&c1)[j],
                               ((const float*)&c2)[j], ((const float*)&c3)[j] };
            float maxA = fmaxf(fmaxf(av[0], av[1]), fmaxf(av[2], av[3]));
            float maxB = fmaxf(fmaxf(bv[0], bv[1]), fmaxf(bv[2], bv[3]));
            float eA[NCLS], eB[NCLS];
            float sA = 0.f, sB = 0.f;
            #pragma unroll
            for (int c = 0; c < NCLS; ++c) {
                eA[c] = __expf(av[c] - maxA); sA += eA[c];
                eB[c] = __expf(bv[c] - maxB); sB += eB[c];
            }
            float lseA = __logf(sA), lseB = __logf(sB);
            float rsA = 1.f / sA, rsB = 1.f / sB;
            float kl = 0.f;
            #pragma unroll
            for (int c = 0; c < NCLS; ++c) {
                float pA  = eA[c] * rsA;
                float pB  = eB[c] * rsB;
                float la  = av[c] - maxA - lseA;   // log pA
                float lb  = bv[c] - maxB - lseB;   // log pB
                float lM  = __logf(0.5f * (pA + pB) + EPS_F);
                kl += pA * (la - lM) + pB * (lb - lM);
            }
            dv[j] = 0.5f * kl;
        }

        *(float4*)(dis + g) = make_float4(dv[0], dv[1], dv[2], dv[3]);

        #pragma unroll
        for (int j = 0; j < 4; ++j) {
            int lbl = (int)lab32[(size_t)(g + j) * lstride];
            unsigned key = f2key(dv[j]);
            #pragma unroll
            for (int c = 0; c < NCLS; ++c) {
                if (lbl == c) {
                    lmin[c] = min(lmin[c], key);
                    lmax[c] = max(lmax[c], key);
                }
            }
        }
    }

    // wave reduce (64 lanes)
    #pragma unroll
    for (int off = 32; off > 0; off >>= 1) {
        #pragma unroll
        for (int c = 0; c < NCLS; ++c) {
            unsigned om = (unsigned)__shfl_xor((int)lmin[c], off);
            unsigned oM = (unsigned)__shfl_xor((int)lmax[c], off);
            lmin[c] = min(lmin[c], om);
            lmax[c] = max(lmax[c], oM);
        }
    }
    if ((threadIdx.x & 63) == 0) {
        #pragma unroll
        for (int c = 0; c < NCLS; ++c) {
            atomicMin(&smin[c], lmin[c]);
            atomicMax(&smax[c], lmax[c]);
        }
    }
    __syncthreads();
    if (threadIdx.x < NCLS) {
        atomicMin(&mink[threadIdx.x], smin[threadIdx.x]);
        atomicMax(&maxk[threadIdx.x], smax[threadIdx.x]);
    }
}

// Fold per-class stats into gamma = base[c] + mult[c] * dis
__global__ void k_stats(const unsigned* __restrict__ mink, const unsigned* __restrict__ maxk,
                        const float* __restrict__ ranks, float* __restrict__ params) {
    int c = threadIdx.x;
    if (c >= NCLS) return;
    unsigned kmin = mink[c], kmax = maxk[c];
    bool present = (kmin != 0xFFFFFFFFu);
    float dmin = present ? key2f(kmin) : 0.0f;
    float dmax = present ? key2f(kmax) : LOG2_F;
    float inter = 1.0f - ranks[c] * (1.0f / (NCLS - 1));
    float base, mult;
    if (dmax > dmin) {
        float inv = 1.0f / (dmax - dmin + EPS_F);
        mult = inter * inv;
        base = 1.0f - mult * dmin;
    } else {
        mult = 0.0f;
        base = 1.0f + 0.5f * inter;
    }
    params[c] = base;
    params[NCLS + c] = mult;
}

// gamma_map = base[lbl] + mult[lbl]*dis  -> written at out + FEAT_ELEMS
__global__ void __launch_bounds__(256)
k_gamma(const unsigned* __restrict__ lab32, const int* __restrict__ i64flag,
        const float* __restrict__ dis, const float* __restrict__ params,
        float* __restrict__ gamma_out) {
    const int q = blockIdx.x * blockDim.x + threadIdx.x;
    const int g = q << 2;
    if (g >= NVOX) return;
    const int lstride = 1 + *i64flag;

    float4 d4 = *(const float4*)(dis + g);
    float ga[4];
    #pragma unroll
    for (int j = 0; j < 4; ++j) {
        int lbl = (int)lab32[(size_t)(g + j) * lstride];
        ga[j] = params[lbl] + params[NCLS + lbl] * ((const float*)&d4)[j];
    }
    *(float4*)(gamma_out + g) = make_float4(ga[0], ga[1], ga[2], ga[3]);
}

// Pure streaming scale: out[e] = feat[e] * gamma[b*S_VOX + v], linear walk.
// One float4 per thread per iteration: each instruction is 64 lanes x 16B
// DENSE (1KB contiguous). Deviations (stride-split R4, thread-adjacent R5)
// both regressed ~25us — keep this form.
__global__ void __launch_bounds__(256)
k_scale(const float* __restrict__ feat, const float* __restrict__ gamma,
        float* __restrict__ out) {
    const size_t nquad = FEAT_ELEMS / 4;          // 16M float4s
    const size_t stride = (size_t)gridDim.x * blockDim.x;
    for (size_t i = (size_t)blockIdx.x * blockDim.x + threadIdx.x; i < nquad;
         i += stride) {
        const size_t e = i << 2;                  // element index
        const int b = (int)(e >> 25);             // e / (NFEAT*S_VOX)
        const int v = (int)(e & (S_VOX - 1));
        f32x4 x = __builtin_nontemporal_load((const f32x4*)(feat + e));
        f32x4 gmm = *(const f32x4*)(gamma + ((size_t)b << 20) + v);
        x *= gmm;
        __builtin_nontemporal_store(x, (f32x4*)(out + e));
    }
}

extern "C" void kernel_launch(void* const* d_in, const int* in_sizes, int n_in,
                              void* d_out, int out_size, void* d_ws, size_t ws_size,
                              hipStream_t stream) {
    const float*    feat  = (const float*)d_in[0];
    const float*    lA    = (const float*)d_in[1];
    const float*    lB    = (const float*)d_in[2];
    const unsigned* lab32 = (const unsigned*)d_in[3];
    const float*    ranks = (const float*)d_in[4];
    float* out = (float*)d_out;

    char* ws = (char*)d_ws;
    unsigned* mink   = (unsigned*)(ws + 0);
    unsigned* maxk   = (unsigned*)(ws + 16);
    int*      flag   = (int*)(ws + 32);
    float*    params = (float*)(ws + 64);
    float*    dis    = (float*)(ws + 256);

    float* gamma_out = out + (size_t)FEAT_ELEMS;

    k_prolog<<<1, 64, 0, stream>>>(lab32, mink, maxk, flag);
    k_dis<<<4096, 256, 0, stream>>>(lA, lB, lab32, flag, dis, mink, maxk);
    k_stats<<<1, 64, 0, stream>>>(mink, maxk, ranks, params);
    k_gamma<<<NVOX / 4 / 256, 256, 0, stream>>>(lab32, flag, dis, params, gamma_out);
    k_scale<<<8192, 256, 0, stream>>>(feat, gamma_out, out);
}

// Round 7
// 135.647 us; speedup vs baseline: 1.6080x; 1.6080x over previous
//
#include <hip/hip_runtime.h>
#include <hip/hip_bf16.h>

// Problem constants (fixed shapes): B=2, F=32, C=4, D=64, H=128, W=128
#define S_VOX  1048576          // D*H*W = 2^20
#define NVOX   2097152          // B * S_VOX
#define NCLS   4
#define NFEAT  32
#define FEAT_ELEMS 67108864     // B*F*S_VOX
#define EPS_F  1e-8f
#define LOG2_F 0.6931471805599453f
#define DIS_BLOCKS 1024

typedef float f32x4 __attribute__((ext_vector_type(4)));

// ---- monotonic float <-> orderable uint key ----
__device__ __forceinline__ unsigned f2key(float f) {
    unsigned u = __float_as_uint(f);
    return (u & 0x80000000u) ? ~u : (u | 0x80000000u);
}
__device__ __forceinline__ float key2f(unsigned k) {
    unsigned u = (k & 0x80000000u) ? (k & 0x7FFFFFFFu) : ~k;
    return __uint_as_float(u);
}

// ws layout (bytes):
//   32      : int      i64flag
//   64      : float    params[8]            (base[4], mult[4])
//   256     : float    dis[NVOX]            (8 MB)
//   256+8MB : unsigned partials[DIS_BLOCKS*8]  (min[4],max[4] per block, 32 KB)

__global__ void k_prolog(const unsigned* __restrict__ lab32, int* __restrict__ flag) {
    int t = threadIdx.x;            // 64 threads
    unsigned even = lab32[2 * t];
    unsigned odd  = lab32[2 * t + 1];
    unsigned long long oddnz  = __ballot(odd  != 0u);
    unsigned long long evennz = __ballot(even != 0u);
    if (t == 0) *flag = (oddnz == 0ull && evennz != 0ull) ? 1 : 0;
}

__global__ void __launch_bounds__(256)
k_dis(const float* __restrict__ lA, const float* __restrict__ lB,
      const unsigned* __restrict__ lab32, const int* __restrict__ i64flag,
      float* __restrict__ dis, unsigned* __restrict__ partials) {
    __shared__ unsigned smin[NCLS], smax[NCLS];
    if (threadIdx.x < NCLS) { smin[threadIdx.x] = 0xFFFFFFFFu; smax[threadIdx.x] = 0u; }
    __syncthreads();

    const int lstride = 1 + *i64flag;   // 1 if int32, 2 if int64 (low word)
    unsigned lmin[NCLS] = {0xFFFFFFFFu, 0xFFFFFFFFu, 0xFFFFFFFFu, 0xFFFFFFFFu};
    unsigned lmax[NCLS] = {0u, 0u, 0u, 0u};

    const int nquad = NVOX / 4;
    for (int q = blockIdx.x * blockDim.x + threadIdx.x; q < nquad;
         q += gridDim.x * blockDim.x) {
        const int g = q << 2;                 // base voxel index
        const int b = g >> 20;                // batch
        const int v = g & (S_VOX - 1);
        const size_t abase = ((size_t)b * NCLS) * S_VOX + v;

        float4 a0 = *(const float4*)(lA + abase);
        float4 a1 = *(const float4*)(lA + abase + S_VOX);
        float4 a2 = *(const float4*)(lA + abase + 2 * (size_t)S_VOX);
        float4 a3 = *(const float4*)(lA + abase + 3 * (size_t)S_VOX);
        float4 c0 = *(const float4*)(lB + abase);
        float4 c1 = *(const float4*)(lB + abase + S_VOX);
        float4 c2 = *(const float4*)(lB + abase + 2 * (size_t)S_VOX);
        float4 c3 = *(const float4*)(lB + abase + 3 * (size_t)S_VOX);

        float dv[4];
        #pragma unroll
        for (int j = 0; j < 4; ++j) {
            float av[NCLS] = { ((const float*)&a0)[j], ((const float*)&a1)[j],
                               ((const float*)&a2)[j], ((const float*)&a3)[j] };
            float bv[NCLS] = { ((const float*)&c0)[j], ((const float*)&c1)[j],
                               ((const float*)&c2)[j], ((const float*)&c3)[j] };
            float maxA = fmaxf(fmaxf(av[0], av[1]), fmaxf(av[2], av[3]));
            float maxB = fmaxf(fmaxf(bv[0], bv[1]), fmaxf(bv[2], bv[3]));
            float eA[NCLS], eB[NCLS];
            float sA = 0.f, sB = 0.f;
            #pragma unroll
            for (int c = 0; c < NCLS; ++c) {
                eA[c] = __expf(av[c] - maxA); sA += eA[c];
                eB[c] = __expf(bv[c] - maxB); sB += eB[c];
            }
            float lseA = __logf(sA), lseB = __logf(sB);
            float rsA = 1.f / sA, rsB = 1.f / sB;
            float kl = 0.f;
            #pragma unroll
            for (int c = 0; c < NCLS; ++c) {
                float pA  = eA[c] * rsA;
                float pB  = eB[c] * rsB;
                float la  = av[c] - maxA - lseA;   // log pA
                float lb  = bv[c] - maxB - lseB;   // log pB
                float lM  = __logf(0.5f * (pA + pB) + EPS_F);
                kl += pA * (la - lM) + pB * (lb - lM);
            }
            dv[j] = 0.5f * kl;
        }

        *(float4*)(dis + g) = make_float4(dv[0], dv[1], dv[2], dv[3]);

        #pragma unroll
        for (int j = 0; j < 4; ++j) {
            int lbl = (int)lab32[(size_t)(g + j) * lstride];
            unsigned key = f2key(dv[j]);
            #pragma unroll
            for (int c = 0; c < NCLS; ++c) {
                if (lbl == c) {
                    lmin[c] = min(lmin[c], key);
                    lmax[c] = max(lmax[c], key);
                }
            }
        }
    }

    // wave reduce (64 lanes)
    #pragma unroll
    for (int off = 32; off > 0; off >>= 1) {
        #pragma unroll
        for (int c = 0; c < NCLS; ++c) {
            unsigned om = (unsigned)__shfl_xor((int)lmin[c], off);
            unsigned oM = (unsigned)__shfl_xor((int)lmax[c], off);
            lmin[c] = min(lmin[c], om);
            lmax[c] = max(lmax[c], oM);
        }
    }
    if ((threadIdx.x & 63) == 0) {
        #pragma unroll
        for (int c = 0; c < NCLS; ++c) {
            atomicMin(&smin[c], lmin[c]);
            atomicMax(&smax[c], lmax[c]);
        }
    }
    __syncthreads();
    // NO global atomics: plain per-block partial store (contention-free).
    if (threadIdx.x < 8) {
        unsigned val = (threadIdx.x < NCLS) ? smin[threadIdx.x] : smax[threadIdx.x - NCLS];
        partials[(size_t)blockIdx.x * 8 + threadIdx.x] = val;
    }
}

// Reduce DIS_BLOCKS partial slots, then fold per-class stats into
// gamma = base[c] + mult[c] * dis.   1 block x 256 threads.
__global__ void __launch_bounds__(256)
k_stats(const unsigned* __restrict__ partials, const float* __restrict__ ranks,
        float* __restrict__ params) {
    __shared__ unsigned red[4][8];      // [wave][min0..3,max0..3]
    const int tid = threadIdx.x;

    unsigned mn[NCLS] = {0xFFFFFFFFu, 0xFFFFFFFFu, 0xFFFFFFFFu, 0xFFFFFFFFu};
    unsigned mx[NCLS] = {0u, 0u, 0u, 0u};
    // 1024 slots / 256 threads = 4 contiguous slots per thread
    #pragma unroll
    for (int s = 0; s < 4; ++s) {
        const unsigned* p = partials + ((size_t)tid * 4 + s) * 8;
        uint4 pmin = *(const uint4*)(p);
        uint4 pmax = *(const uint4*)(p + 4);
        mn[0] = min(mn[0], pmin.x); mn[1] = min(mn[1], pmin.y);
        mn[2] = min(mn[2], pmin.z); mn[3] = min(mn[3], pmin.w);
        mx[0] = max(mx[0], pmax.x); mx[1] = max(mx[1], pmax.y);
        mx[2] = max(mx[2], pmax.z); mx[3] = max(mx[3], pmax.w);
    }
    #pragma unroll
    for (int off = 32; off > 0; off >>= 1) {
        #pragma unroll
        for (int c = 0; c < NCLS; ++c) {
            unsigned om = (unsigned)__shfl_xor((int)mn[c], off);
            unsigned oM = (unsigned)__shfl_xor((int)mx[c], off);
            mn[c] = min(mn[c], om);
            mx[c] = max(mx[c], oM);
        }
    }
    if ((tid & 63) == 0) {
        const int w = tid >> 6;
        #pragma unroll
        for (int c = 0; c < NCLS; ++c) { red[w][c] = mn[c]; red[w][NCLS + c] = mx[c]; }
    }
    __syncthreads();
    if (tid < NCLS) {
        const int c = tid;
        unsigned kmin = 0xFFFFFFFFu, kmax = 0u;
        #pragma unroll
        for (int w = 0; w < 4; ++w) {
            kmin = min(kmin, red[w][c]);
            kmax = max(kmax, red[w][NCLS + c]);
        }
        bool present = (kmin != 0xFFFFFFFFu);
        float dmin = present ? key2f(kmin) : 0.0f;
        float dmax = present ? key2f(kmax) : LOG2_F;
        float inter = 1.0f - ranks[c] * (1.0f / (NCLS - 1));
        float base, mult;
        if (dmax > dmin) {
            float inv = 1.0f / (dmax - dmin + EPS_F);
            mult = inter * inv;
            base = 1.0f - mult * dmin;
        } else {
            mult = 0.0f;
            base = 1.0f + 0.5f * inter;
        }
        params[c] = base;
        params[NCLS + c] = mult;
    }
}

// gamma_map = base[lbl] + mult[lbl]*dis  -> written at out + FEAT_ELEMS
__global__ void __launch_bounds__(256)
k_gamma(const unsigned* __restrict__ lab32, const int* __restrict__ i64flag,
        const float* __restrict__ dis, const float* __restrict__ params,
        float* __restrict__ gamma_out) {
    const int q = blockIdx.x * blockDim.x + threadIdx.x;
    const int g = q << 2;
    if (g >= NVOX) return;
    const int lstride = 1 + *i64flag;

    float4 d4 = *(const float4*)(dis + g);
    float ga[4];
    #pragma unroll
    for (int j = 0; j < 4; ++j) {
        int lbl = (int)lab32[(size_t)(g + j) * lstride];
        ga[j] = params[lbl] + params[NCLS + lbl] * ((const float*)&d4)[j];
    }
    *(float4*)(gamma_out + g) = make_float4(ga[0], ga[1], ga[2], ga[3]);
}

// Pure streaming scale: out[e] = feat[e] * gamma[b*S_VOX + v], linear walk.
// One float4 per thread per iteration: each instruction is 64 lanes x 16B
// DENSE (1KB contiguous). Deviations (stride-split R4, thread-adjacent R5)
// both regressed ~25us — keep this form.
__global__ void __launch_bounds__(256)
k_scale(const float* __restrict__ feat, const float* __restrict__ gamma,
        float* __restrict__ out) {
    const size_t nquad = FEAT_ELEMS / 4;          // 16M float4s
    const size_t stride = (size_t)gridDim.x * blockDim.x;
    for (size_t i = (size_t)blockIdx.x * blockDim.x + threadIdx.x; i < nquad;
         i += stride) {
        const size_t e = i << 2;                  // element index
        const int b = (int)(e >> 25);             // e / (NFEAT*S_VOX)
        const int v = (int)(e & (S_VOX - 1));
        f32x4 x = __builtin_nontemporal_load((const f32x4*)(feat + e));
        f32x4 gmm = *(const f32x4*)(gamma + ((size_t)b << 20) + v);
        x *= gmm;
        __builtin_nontemporal_store(x, (f32x4*)(out + e));
    }
}

extern "C" void kernel_launch(void* const* d_in, const int* in_sizes, int n_in,
                              void* d_out, int out_size, void* d_ws, size_t ws_size,
                              hipStream_t stream) {
    const float*    feat  = (const float*)d_in[0];
    const float*    lA    = (const float*)d_in[1];
    const float*    lB    = (const float*)d_in[2];
    const unsigned* lab32 = (const unsigned*)d_in[3];
    const float*    ranks = (const float*)d_in[4];
    float* out = (float*)d_out;

    char* ws = (char*)d_ws;
    int*      flag     = (int*)(ws + 32);
    float*    params   = (float*)(ws + 64);
    float*    dis      = (float*)(ws + 256);
    unsigned* partials = (unsigned*)(ws + 256 + (size_t)NVOX * 4);   // 32 KB

    float* gamma_out = out + (size_t)FEAT_ELEMS;

    k_prolog<<<1, 64, 0, stream>>>(lab32, flag);
    k_dis<<<DIS_BLOCKS, 256, 0, stream>>>(lA, lB, lab32, flag, dis, partials);
    k_stats<<<1, 256, 0, stream>>>(partials, ranks, params);
    k_gamma<<<NVOX / 4 / 256, 256, 0, stream>>>(lab32, flag, dis, params, gamma_out);
    k_scale<<<8192, 256, 0, stream>>>(feat, gamma_out, out);
}

// Round 8
// 130.691 us; speedup vs baseline: 1.6690x; 1.0379x over previous
//
#include <hip/hip_runtime.h>
#include <hip/hip_bf16.h>

// Problem constants (fixed shapes): B=2, F=32, C=4, D=64, H=128, W=128
#define S_VOX  1048576          // D*H*W = 2^20
#define NVOX   2097152          // B * S_VOX
#define NCLS   4
#define NFEAT  32
#define FEAT_ELEMS 67108864     // B*F*S_VOX
#define EPS_F  1e-8f
#define LOG2_F 0.6931471805599453f
#define DIS_BLOCKS 1024

typedef float f32x4 __attribute__((ext_vector_type(4)));

// ---- monotonic float <-> orderable uint key ----
__device__ __forceinline__ unsigned f2key(float f) {
    unsigned u = __float_as_uint(f);
    return (u & 0x80000000u) ? ~u : (u | 0x80000000u);
}
__device__ __forceinline__ float key2f(unsigned k) {
    unsigned u = (k & 0x80000000u) ? (k & 0x7FFFFFFFu) : ~k;
    return __uint_as_float(u);
}

// ws layout (bytes):
//   32      : int      i64flag
//   64      : float    params[8]            (base[4], mult[4])
//   256     : float    dis[NVOX]            (8 MB)
//   256+8MB : unsigned partials[DIS_BLOCKS*8]  (min[4],max[4] per block, 32 KB)

__global__ void k_prolog(const unsigned* __restrict__ lab32, int* __restrict__ flag) {
    int t = threadIdx.x;            // 64 threads
    unsigned even = lab32[2 * t];
    unsigned odd  = lab32[2 * t + 1];
    unsigned long long oddnz  = __ballot(odd  != 0u);
    unsigned long long evennz = __ballot(even != 0u);
    if (t == 0) *flag = (oddnz == 0ull && evennz != 0ull) ? 1 : 0;
}

__global__ void __launch_bounds__(256)
k_dis(const float* __restrict__ lA, const float* __restrict__ lB,
      const unsigned* __restrict__ lab32, const int* __restrict__ i64flag,
      float* __restrict__ dis, unsigned* __restrict__ partials) {
    __shared__ unsigned smin[NCLS], smax[NCLS];
    if (threadIdx.x < NCLS) { smin[threadIdx.x] = 0xFFFFFFFFu; smax[threadIdx.x] = 0u; }
    __syncthreads();

    const int lstride = 1 + *i64flag;   // 1 if int32, 2 if int64 (low word)
    unsigned lmin[NCLS] = {0xFFFFFFFFu, 0xFFFFFFFFu, 0xFFFFFFFFu, 0xFFFFFFFFu};
    unsigned lmax[NCLS] = {0u, 0u, 0u, 0u};

    const int nquad = NVOX / 4;
    for (int q = blockIdx.x * blockDim.x + threadIdx.x; q < nquad;
         q += gridDim.x * blockDim.x) {
        const int g = q << 2;                 // base voxel index
        const int b = g >> 20;                // batch
        const int v = g & (S_VOX - 1);
        const size_t abase = ((size_t)b * NCLS) * S_VOX + v;

        float4 a0 = *(const float4*)(lA + abase);
        float4 a1 = *(const float4*)(lA + abase + S_VOX);
        float4 a2 = *(const float4*)(lA + abase + 2 * (size_t)S_VOX);
        float4 a3 = *(const float4*)(lA + abase + 3 * (size_t)S_VOX);
        float4 c0 = *(const float4*)(lB + abase);
        float4 c1 = *(const float4*)(lB + abase + S_VOX);
        float4 c2 = *(const float4*)(lB + abase + 2 * (size_t)S_VOX);
        float4 c3 = *(const float4*)(lB + abase + 3 * (size_t)S_VOX);

        float dv[4];
        #pragma unroll
        for (int j = 0; j < 4; ++j) {
            float av[NCLS] = { ((const float*)&a0)[j], ((const float*)&a1)[j],
                               ((const float*)&a2)[j], ((const float*)&a3)[j] };
            float bv[NCLS] = { ((const float*)&c0)[j], ((const float*)&c1)[j],
                               ((const float*)&c2)[j], ((const float*)&c3)[j] };
            float maxA = fmaxf(fmaxf(av[0], av[1]), fmaxf(av[2], av[3]));
            float maxB = fmaxf(fmaxf(bv[0], bv[1]), fmaxf(bv[2], bv[3]));
            float eA[NCLS], eB[NCLS];
            float sA = 0.f, sB = 0.f;
            #pragma unroll
            for (int c = 0; c < NCLS; ++c) {
                eA[c] = __expf(av[c] - maxA); sA += eA[c];
                eB[c] = __expf(bv[c] - maxB); sB += eB[c];
            }
            float lseA = __logf(sA), lseB = __logf(sB);
            float rsA = 1.f / sA, rsB = 1.f / sB;
            float kl = 0.f;
            #pragma unroll
            for (int c = 0; c < NCLS; ++c) {
                float pA  = eA[c] * rsA;
                float pB  = eB[c] * rsB;
                float la  = av[c] - maxA - lseA;   // log pA
                float lb  = bv[c] - maxB - lseB;   // log pB
                float lM  = __logf(0.5f * (pA + pB) + EPS_F);
                kl += pA * (la - lM) + pB * (lb - lM);
            }
            dv[j] = 0.5f * kl;
        }

        *(float4*)(dis + g) = make_float4(dv[0], dv[1], dv[2], dv[3]);

        #pragma unroll
        for (int j = 0; j < 4; ++j) {
            int lbl = (int)lab32[(size_t)(g + j) * lstride];
            unsigned key = f2key(dv[j]);
            #pragma unroll
            for (int c = 0; c < NCLS; ++c) {
                if (lbl == c) {
                    lmin[c] = min(lmin[c], key);
                    lmax[c] = max(lmax[c], key);
                }
            }
        }
    }

    // wave reduce (64 lanes)
    #pragma unroll
    for (int off = 32; off > 0; off >>= 1) {
        #pragma unroll
        for (int c = 0; c < NCLS; ++c) {
            unsigned om = (unsigned)__shfl_xor((int)lmin[c], off);
            unsigned oM = (unsigned)__shfl_xor((int)lmax[c], off);
            lmin[c] = min(lmin[c], om);
            lmax[c] = max(lmax[c], oM);
        }
    }
    if ((threadIdx.x & 63) == 0) {
        #pragma unroll
        for (int c = 0; c < NCLS; ++c) {
            atomicMin(&smin[c], lmin[c]);
            atomicMax(&smax[c], lmax[c]);
        }
    }
    __syncthreads();
    // NO global atomics: plain per-block partial store (contention-free).
    if (threadIdx.x < 8) {
        unsigned val = (threadIdx.x < NCLS) ? smin[threadIdx.x] : smax[threadIdx.x - NCLS];
        partials[(size_t)blockIdx.x * 8 + threadIdx.x] = val;
    }
}

// Reduce DIS_BLOCKS partial slots, then fold per-class stats into
// gamma = base[c] + mult[c] * dis.   1 block x 256 threads.
__global__ void __launch_bounds__(256)
k_stats(const unsigned* __restrict__ partials, const float* __restrict__ ranks,
        float* __restrict__ params) {
    __shared__ unsigned red[4][8];      // [wave][min0..3,max0..3]
    const int tid = threadIdx.x;

    unsigned mn[NCLS] = {0xFFFFFFFFu, 0xFFFFFFFFu, 0xFFFFFFFFu, 0xFFFFFFFFu};
    unsigned mx[NCLS] = {0u, 0u, 0u, 0u};
    // 1024 slots / 256 threads = 4 contiguous slots per thread
    #pragma unroll
    for (int s = 0; s < 4; ++s) {
        const unsigned* p = partials + ((size_t)tid * 4 + s) * 8;
        uint4 pmin = *(const uint4*)(p);
        uint4 pmax = *(const uint4*)(p + 4);
        mn[0] = min(mn[0], pmin.x); mn[1] = min(mn[1], pmin.y);
        mn[2] = min(mn[2], pmin.z); mn[3] = min(mn[3], pmin.w);
        mx[0] = max(mx[0], pmax.x); mx[1] = max(mx[1], pmax.y);
        mx[2] = max(mx[2], pmax.z); mx[3] = max(mx[3], pmax.w);
    }
    #pragma unroll
    for (int off = 32; off > 0; off >>= 1) {
        #pragma unroll
        for (int c = 0; c < NCLS; ++c) {
            unsigned om = (unsigned)__shfl_xor((int)mn[c], off);
            unsigned oM = (unsigned)__shfl_xor((int)mx[c], off);
            mn[c] = min(mn[c], om);
            mx[c] = max(mx[c], oM);
        }
    }
    if ((tid & 63) == 0) {
        const int w = tid >> 6;
        #pragma unroll
        for (int c = 0; c < NCLS; ++c) { red[w][c] = mn[c]; red[w][NCLS + c] = mx[c]; }
    }
    __syncthreads();
    if (tid < NCLS) {
        const int c = tid;
        unsigned kmin = 0xFFFFFFFFu, kmax = 0u;
        #pragma unroll
        for (int w = 0; w < 4; ++w) {
            kmin = min(kmin, red[w][c]);
            kmax = max(kmax, red[w][NCLS + c]);
        }
        bool present = (kmin != 0xFFFFFFFFu);
        float dmin = present ? key2f(kmin) : 0.0f;
        float dmax = present ? key2f(kmax) : LOG2_F;
        float inter = 1.0f - ranks[c] * (1.0f / (NCLS - 1));
        float base, mult;
        if (dmax > dmin) {
            float inv = 1.0f / (dmax - dmin + EPS_F);
            mult = inter * inv;
            base = 1.0f - mult * dmin;
        } else {
            mult = 0.0f;
            base = 1.0f + 0.5f * inter;
        }
        params[c] = base;
        params[NCLS + c] = mult;
    }
}

// gamma_map = base[lbl] + mult[lbl]*dis  -> written at out + FEAT_ELEMS
__global__ void __launch_bounds__(256)
k_gamma(const unsigned* __restrict__ lab32, const int* __restrict__ i64flag,
        const float* __restrict__ dis, const float* __restrict__ params,
        float* __restrict__ gamma_out) {
    const int q = blockIdx.x * blockDim.x + threadIdx.x;
    const int g = q << 2;
    if (g >= NVOX) return;
    const int lstride = 1 + *i64flag;

    float4 d4 = *(const float4*)(dis + g);
    float ga[4];
    #pragma unroll
    for (int j = 0; j < 4; ++j) {
        int lbl = (int)lab32[(size_t)(g + j) * lstride];
        ga[j] = params[lbl] + params[NCLS + lbl] * ((const float*)&d4)[j];
    }
    *(float4*)(gamma_out + g) = make_float4(ga[0], ga[1], ga[2], ga[3]);
}

// Pure streaming scale: out[e] = feat[e] * gamma[b*S_VOX + v].
// Block-adjacent x2 unroll: each block owns chunks of 512 quads; thread t
// does quads chunk+t and chunk+256+t. Every instruction stays 64 lanes x 16B
// DENSE (1KB contiguous); 4 independent loads + 2 stores in flight/thread.
// (stride-split R4 and thread-adjacent R5 both regressed — keep density.)
__global__ void __launch_bounds__(256)
k_scale(const float* __restrict__ feat, const float* __restrict__ gamma,
        float* __restrict__ out) {
    const size_t nchunk = FEAT_ELEMS / 4 / 512;   // 32768 chunks of 512 quads
    for (size_t cb = blockIdx.x; cb < nchunk; cb += gridDim.x) {
        const size_t q0 = cb * 512 + threadIdx.x;
        const size_t e0 = q0 << 2;
        const size_t e1 = e0 + 1024;              // +256 quads
        const size_t g0 = ((e0 >> 25) << 20) + (e0 & (size_t)(S_VOX - 1));
        const size_t g1 = ((e1 >> 25) << 20) + (e1 & (size_t)(S_VOX - 1));
        f32x4 x0 = __builtin_nontemporal_load((const f32x4*)(feat + e0));
        f32x4 x1 = __builtin_nontemporal_load((const f32x4*)(feat + e1));
        f32x4 m0 = *(const f32x4*)(gamma + g0);
        f32x4 m1 = *(const f32x4*)(gamma + g1);
        __builtin_nontemporal_store(x0 * m0, (f32x4*)(out + e0));
        __builtin_nontemporal_store(x1 * m1, (f32x4*)(out + e1));
    }
}

extern "C" void kernel_launch(void* const* d_in, const int* in_sizes, int n_in,
                              void* d_out, int out_size, void* d_ws, size_t ws_size,
                              hipStream_t stream) {
    const float*    feat  = (const float*)d_in[0];
    const float*    lA    = (const float*)d_in[1];
    const float*    lB    = (const float*)d_in[2];
    const unsigned* lab32 = (const unsigned*)d_in[3];
    const float*    ranks = (const float*)d_in[4];
    float* out = (float*)d_out;

    char* ws = (char*)d_ws;
    int*      flag     = (int*)(ws + 32);
    float*    params   = (float*)(ws + 64);
    float*    dis      = (float*)(ws + 256);
    unsigned* partials = (unsigned*)(ws + 256 + (size_t)NVOX * 4);   // 32 KB

    float* gamma_out = out + (size_t)FEAT_ELEMS;

    k_prolog<<<1, 64, 0, stream>>>(lab32, flag);
    k_dis<<<DIS_BLOCKS, 256, 0, stream>>>(lA, lB, lab32, flag, dis, partials);
    k_stats<<<1, 256, 0, stream>>>(partials, ranks, params);
    k_gamma<<<NVOX / 4 / 256, 256, 0, stream>>>(lab32, flag, dis, params, gamma_out);
    k_scale<<<8192, 256, 0, stream>>>(feat, gamma_out, out);
}

// Round 9
// 128.321 us; speedup vs baseline: 1.6998x; 1.0185x over previous
//
#include <hip/hip_runtime.h>
#include <hip/hip_bf16.h>

// Problem constants (fixed shapes): B=2, F=32, C=4, D=64, H=128, W=128
#define S_VOX  1048576          // D*H*W = 2^20
#define NVOX   2097152          // B * S_VOX
#define NCLS   4
#define NFEAT  32
#define FEAT_ELEMS 67108864     // B*F*S_VOX
#define EPS_F  1e-8f
#define LOG2_F 0.6931471805599453f
#define DIS_BLOCKS 1024

typedef float f32x4 __attribute__((ext_vector_type(4)));

// ---- monotonic float <-> orderable uint key ----
__device__ __forceinline__ unsigned f2key(float f) {
    unsigned u = __float_as_uint(f);
    return (u & 0x80000000u) ? ~u : (u | 0x80000000u);
}
__device__ __forceinline__ float key2f(unsigned k) {
    unsigned u = (k & 0x80000000u) ? (k & 0x7FFFFFFFu) : ~k;
    return __uint_as_float(u);
}

// ws layout (bytes):
//   32      : int      i64flag
//   64      : float    params[8]            (base[4], mult[4])
//   256     : float    dis[NVOX]            (8 MB)
//   256+8MB : unsigned partials[DIS_BLOCKS*8]  (min[4],max[4] per block, 32 KB)

__global__ void k_prolog(const unsigned* __restrict__ lab32, int* __restrict__ flag) {
    int t = threadIdx.x;            // 64 threads
    unsigned even = lab32[2 * t];
    unsigned odd  = lab32[2 * t + 1];
    unsigned long long oddnz  = __ballot(odd  != 0u);
    unsigned long long evennz = __ballot(even != 0u);
    if (t == 0) *flag = (oddnz == 0ull && evennz != 0ull) ? 1 : 0;
}

__global__ void __launch_bounds__(256)
k_dis(const float* __restrict__ lA, const float* __restrict__ lB,
      const unsigned* __restrict__ lab32, const int* __restrict__ i64flag,
      float* __restrict__ dis, unsigned* __restrict__ partials) {
    __shared__ unsigned smin[NCLS], smax[NCLS];
    if (threadIdx.x < NCLS) { smin[threadIdx.x] = 0xFFFFFFFFu; smax[threadIdx.x] = 0u; }
    __syncthreads();

    const int lstride = 1 + *i64flag;   // 1 if int32, 2 if int64 (low word)
    unsigned lmin[NCLS] = {0xFFFFFFFFu, 0xFFFFFFFFu, 0xFFFFFFFFu, 0xFFFFFFFFu};
    unsigned lmax[NCLS] = {0u, 0u, 0u, 0u};

    const int nquad = NVOX / 4;
    for (int q = blockIdx.x * blockDim.x + threadIdx.x; q < nquad;
         q += gridDim.x * blockDim.x) {
        const int g = q << 2;                 // base voxel index
        const int b = g >> 20;                // batch
        const int v = g & (S_VOX - 1);
        const size_t abase = ((size_t)b * NCLS) * S_VOX + v;

        float4 a0 = *(const float4*)(lA + abase);
        float4 a1 = *(const float4*)(lA + abase + S_VOX);
        float4 a2 = *(const float4*)(lA + abase + 2 * (size_t)S_VOX);
        float4 a3 = *(const float4*)(lA + abase + 3 * (size_t)S_VOX);
        float4 c0 = *(const float4*)(lB + abase);
        float4 c1 = *(const float4*)(lB + abase + S_VOX);
        float4 c2 = *(const float4*)(lB + abase + 2 * (size_t)S_VOX);
        float4 c3 = *(const float4*)(lB + abase + 3 * (size_t)S_VOX);

        float dv[4];
        #pragma unroll
        for (int j = 0; j < 4; ++j) {
            float av[NCLS] = { ((const float*)&a0)[j], ((const float*)&a1)[j],
                               ((const float*)&a2)[j], ((const float*)&a3)[j] };
            float bv[NCLS] = { ((const float*)&c0)[j], ((const float*)&c1)[j],
                               ((const float*)&c2)[j], ((const float*)&c3)[j] };
            float maxA = fmaxf(fmaxf(av[0], av[1]), fmaxf(av[2], av[3]));
            float maxB = fmaxf(fmaxf(bv[0], bv[1]), fmaxf(bv[2], bv[3]));
            float eA[NCLS], eB[NCLS];
            float sA = 0.f, sB = 0.f;
            #pragma unroll
            for (int c = 0; c < NCLS; ++c) {
                eA[c] = __expf(av[c] - maxA); sA += eA[c];
                eB[c] = __expf(bv[c] - maxB); sB += eB[c];
            }
            float lseA = __logf(sA), lseB = __logf(sB);
            float rsA = 1.f / sA, rsB = 1.f / sB;
            float kl = 0.f;
            #pragma unroll
            for (int c = 0; c < NCLS; ++c) {
                float pA  = eA[c] * rsA;
                float pB  = eB[c] * rsB;
                float la  = av[c] - maxA - lseA;   // log pA
                float lb  = bv[c] - maxB - lseB;   // log pB
                float lM  = __logf(0.5f * (pA + pB) + EPS_F);
                kl += pA * (la - lM) + pB * (lb - lM);
            }
            dv[j] = 0.5f * kl;
        }

        *(float4*)(dis + g) = make_float4(dv[0], dv[1], dv[2], dv[3]);

        #pragma unroll
        for (int j = 0; j < 4; ++j) {
            int lbl = (int)lab32[(size_t)(g + j) * lstride];
            unsigned key = f2key(dv[j]);
            #pragma unroll
            for (int c = 0; c < NCLS; ++c) {
                if (lbl == c) {
                    lmin[c] = min(lmin[c], key);
                    lmax[c] = max(lmax[c], key);
                }
            }
        }
    }

    // wave reduce (64 lanes)
    #pragma unroll
    for (int off = 32; off > 0; off >>= 1) {
        #pragma unroll
        for (int c = 0; c < NCLS; ++c) {
            unsigned om = (unsigned)__shfl_xor((int)lmin[c], off);
            unsigned oM = (unsigned)__shfl_xor((int)lmax[c], off);
            lmin[c] = min(lmin[c], om);
            lmax[c] = max(lmax[c], oM);
        }
    }
    if ((threadIdx.x & 63) == 0) {
        #pragma unroll
        for (int c = 0; c < NCLS; ++c) {
            atomicMin(&smin[c], lmin[c]);
            atomicMax(&smax[c], lmax[c]);
        }
    }
    __syncthreads();
    // NO global atomics: plain per-block partial store (contention-free).
    if (threadIdx.x < 8) {
        unsigned val = (threadIdx.x < NCLS) ? smin[threadIdx.x] : smax[threadIdx.x - NCLS];
        partials[(size_t)blockIdx.x * 8 + threadIdx.x] = val;
    }
}

// Reduce DIS_BLOCKS partial slots, then fold per-class stats into
// gamma = base[c] + mult[c] * dis.   1 block x 256 threads.
__global__ void __launch_bounds__(256)
k_stats(const unsigned* __restrict__ partials, const float* __restrict__ ranks,
        float* __restrict__ params) {
    __shared__ unsigned red[4][8];      // [wave][min0..3,max0..3]
    const int tid = threadIdx.x;

    unsigned mn[NCLS] = {0xFFFFFFFFu, 0xFFFFFFFFu, 0xFFFFFFFFu, 0xFFFFFFFFu};
    unsigned mx[NCLS] = {0u, 0u, 0u, 0u};
    // 1024 slots / 256 threads = 4 contiguous slots per thread
    #pragma unroll
    for (int s = 0; s < 4; ++s) {
        const unsigned* p = partials + ((size_t)tid * 4 + s) * 8;
        uint4 pmin = *(const uint4*)(p);
        uint4 pmax = *(const uint4*)(p + 4);
        mn[0] = min(mn[0], pmin.x); mn[1] = min(mn[1], pmin.y);
        mn[2] = min(mn[2], pmin.z); mn[3] = min(mn[3], pmin.w);
        mx[0] = max(mx[0], pmax.x); mx[1] = max(mx[1], pmax.y);
        mx[2] = max(mx[2], pmax.z); mx[3] = max(mx[3], pmax.w);
    }
    #pragma unroll
    for (int off = 32; off > 0; off >>= 1) {
        #pragma unroll
        for (int c = 0; c < NCLS; ++c) {
            unsigned om = (unsigned)__shfl_xor((int)mn[c], off);
            unsigned oM = (unsigned)__shfl_xor((int)mx[c], off);
            mn[c] = min(mn[c], om);
            mx[c] = max(mx[c], oM);
        }
    }
    if ((tid & 63) == 0) {
        const int w = tid >> 6;
        #pragma unroll
        for (int c = 0; c < NCLS; ++c) { red[w][c] = mn[c]; red[w][NCLS + c] = mx[c]; }
    }
    __syncthreads();
    if (tid < NCLS) {
        const int c = tid;
        unsigned kmin = 0xFFFFFFFFu, kmax = 0u;
        #pragma unroll
        for (int w = 0; w < 4; ++w) {
            kmin = min(kmin, red[w][c]);
            kmax = max(kmax, red[w][NCLS + c]);
        }
        bool present = (kmin != 0xFFFFFFFFu);
        float dmin = present ? key2f(kmin) : 0.0f;
        float dmax = present ? key2f(kmax) : LOG2_F;
        float inter = 1.0f - ranks[c] * (1.0f / (NCLS - 1));
        float base, mult;
        if (dmax > dmin) {
            float inv = 1.0f / (dmax - dmin + EPS_F);
            mult = inter * inv;
            base = 1.0f - mult * dmin;
        } else {
            mult = 0.0f;
            base = 1.0f + 0.5f * inter;
        }
        params[c] = base;
        params[NCLS + c] = mult;
    }
}

// gamma_map = base[lbl] + mult[lbl]*dis  -> written at out + FEAT_ELEMS
__global__ void __launch_bounds__(256)
k_gamma(const unsigned* __restrict__ lab32, const int* __restrict__ i64flag,
        const float* __restrict__ dis, const float* __restrict__ params,
        float* __restrict__ gamma_out) {
    const int q = blockIdx.x * blockDim.x + threadIdx.x;
    const int g = q << 2;
    if (g >= NVOX) return;
    const int lstride = 1 + *i64flag;

    float4 d4 = *(const float4*)(dis + g);
    float ga[4];
    #pragma unroll
    for (int j = 0; j < 4; ++j) {
        int lbl = (int)lab32[(size_t)(g + j) * lstride];
        ga[j] = params[lbl] + params[NCLS + lbl] * ((const float*)&d4)[j];
    }
    *(float4*)(gamma_out + g) = make_float4(ga[0], ga[1], ga[2], ga[3]);
}

// Pure streaming scale: out[e] = feat[e] * gamma[b*S_VOX + v].
// Block-adjacent x4 unroll: each block owns chunks of 1024 quads; thread t
// does quads chunk + {0,256,512,768} + t. Every instruction stays 64 lanes
// x 16B DENSE (1KB contiguous); 8 independent loads + 4 stores in flight.
// (stride-split R4 and thread-adjacent R5 both regressed — keep density.)
__global__ void __launch_bounds__(256)
k_scale(const float* __restrict__ feat, const float* __restrict__ gamma,
        float* __restrict__ out) {
    const size_t nchunk = FEAT_ELEMS / 4 / 1024;  // 16384 chunks of 1024 quads
    for (size_t cb = blockIdx.x; cb < nchunk; cb += gridDim.x) {
        const size_t e0 = (cb * 1024 + threadIdx.x) << 2;
        const size_t e1 = e0 + 1024;              // +256 quads
        const size_t e2 = e0 + 2048;
        const size_t e3 = e0 + 3072;
        const size_t g0 = ((e0 >> 25) << 20) + (e0 & (size_t)(S_VOX - 1));
        const size_t g1 = ((e1 >> 25) << 20) + (e1 & (size_t)(S_VOX - 1));
        const size_t g2 = ((e2 >> 25) << 20) + (e2 & (size_t)(S_VOX - 1));
        const size_t g3 = ((e3 >> 25) << 20) + (e3 & (size_t)(S_VOX - 1));
        f32x4 x0 = __builtin_nontemporal_load((const f32x4*)(feat + e0));
        f32x4 x1 = __builtin_nontemporal_load((const f32x4*)(feat + e1));
        f32x4 x2 = __builtin_nontemporal_load((const f32x4*)(feat + e2));
        f32x4 x3 = __builtin_nontemporal_load((const f32x4*)(feat + e3));
        f32x4 m0 = *(const f32x4*)(gamma + g0);
        f32x4 m1 = *(const f32x4*)(gamma + g1);
        f32x4 m2 = *(const f32x4*)(gamma + g2);
        f32x4 m3 = *(const f32x4*)(gamma + g3);
        __builtin_nontemporal_store(x0 * m0, (f32x4*)(out + e0));
        __builtin_nontemporal_store(x1 * m1, (f32x4*)(out + e1));
        __builtin_nontemporal_store(x2 * m2, (f32x4*)(out + e2));
        __builtin_nontemporal_store(x3 * m3, (f32x4*)(out + e3));
    }
}

extern "C" void kernel_launch(void* const* d_in, const int* in_sizes, int n_in,
                              void* d_out, int out_size, void* d_ws, size_t ws_size,
                              hipStream_t stream) {
    const float*    feat  = (const float*)d_in[0];
    const float*    lA    = (const float*)d_in[1];
    const float*    lB    = (const float*)d_in[2];
    const unsigned* lab32 = (const unsigned*)d_in[3];
    const float*    ranks = (const float*)d_in[4];
    float* out = (float*)d_out;

    char* ws = (char*)d_ws;
    int*      flag     = (int*)(ws + 32);
    float*    params   = (float*)(ws + 64);
    float*    dis      = (float*)(ws + 256);
    unsigned* partials = (unsigned*)(ws + 256 + (size_t)NVOX * 4);   // 32 KB

    float* gamma_out = out + (size_t)FEAT_ELEMS;

    k_prolog<<<1, 64, 0, stream>>>(lab32, flag);
    k_dis<<<DIS_BLOCKS, 256, 0, stream>>>(lA, lB, lab32, flag, dis, partials);
    k_stats<<<1, 256, 0, stream>>>(partials, ranks, params);
    k_gamma<<<NVOX / 4 / 256, 256, 0, stream>>>(lab32, flag, dis, params, gamma_out);
    k_scale<<<8192, 256, 0, stream>>>(feat, gamma_out, out);
}

// Round 10
// 124.569 us; speedup vs baseline: 1.7510x; 1.0301x over previous
//
#include <hip/hip_runtime.h>
#include <hip/hip_bf16.h>

// Problem constants (fixed shapes): B=2, F=32, C=4, D=64, H=128, W=128
#define S_VOX  1048576          // D*H*W = 2^20
#define NVOX   2097152          // B * S_VOX
#define NCLS   4
#define NFEAT  32
#define FEAT_ELEMS 67108864     // B*F*S_VOX
#define EPS_F  1e-8f
#define LOG2_F 0.6931471805599453f
#define DIS_BLOCKS 1024

typedef float f32x4 __attribute__((ext_vector_type(4)));

// ---- monotonic float <-> orderable uint key ----
__device__ __forceinline__ unsigned f2key(float f) {
    unsigned u = __float_as_uint(f);
    return (u & 0x80000000u) ? ~u : (u | 0x80000000u);
}
__device__ __forceinline__ float key2f(unsigned k) {
    unsigned u = (k & 0x80000000u) ? (k & 0x7FFFFFFFu) : ~k;
    return __uint_as_float(u);
}

// ws layout (bytes):
//   32      : int      i64flag
//   64      : float    params[8]            (base[4], mult[4])
//   256     : unsigned disp[NVOX]           (8 MB: dis bits with label packed
//                                            into low 2 mantissa bits)
//   256+8MB : unsigned partials[DIS_BLOCKS*8]  (min[4],max[4] per block, 32 KB)

__global__ void k_prolog(const unsigned* __restrict__ lab32, int* __restrict__ flag) {
    int t = threadIdx.x;            // 64 threads
    unsigned even = lab32[2 * t];
    unsigned odd  = lab32[2 * t + 1];
    unsigned long long oddnz  = __ballot(odd  != 0u);
    unsigned long long evennz = __ballot(even != 0u);
    if (t == 0) *flag = (oddnz == 0ull && evennz != 0ull) ? 1 : 0;
}

__global__ void __launch_bounds__(256)
k_dis(const float* __restrict__ lA, const float* __restrict__ lB,
      const unsigned* __restrict__ lab32, const int* __restrict__ i64flag,
      unsigned* __restrict__ disp, unsigned* __restrict__ partials) {
    __shared__ unsigned smin[NCLS], smax[NCLS];
    if (threadIdx.x < NCLS) { smin[threadIdx.x] = 0xFFFFFFFFu; smax[threadIdx.x] = 0u; }
    __syncthreads();

    const int lstride = 1 + *i64flag;   // 1 if int32, 2 if int64 (low word)
    unsigned lmin[NCLS] = {0xFFFFFFFFu, 0xFFFFFFFFu, 0xFFFFFFFFu, 0xFFFFFFFFu};
    unsigned lmax[NCLS] = {0u, 0u, 0u, 0u};

    const int nquad = NVOX / 4;
    for (int q = blockIdx.x * blockDim.x + threadIdx.x; q < nquad;
         q += gridDim.x * blockDim.x) {
        const int g = q << 2;                 // base voxel index
        const int b = g >> 20;                // batch
        const int v = g & (S_VOX - 1);
        const size_t abase = ((size_t)b * NCLS) * S_VOX + v;

        float4 a0 = *(const float4*)(lA + abase);
        float4 a1 = *(const float4*)(lA + abase + S_VOX);
        float4 a2 = *(const float4*)(lA + abase + 2 * (size_t)S_VOX);
        float4 a3 = *(const float4*)(lA + abase + 3 * (size_t)S_VOX);
        float4 c0 = *(const float4*)(lB + abase);
        float4 c1 = *(const float4*)(lB + abase + S_VOX);
        float4 c2 = *(const float4*)(lB + abase + 2 * (size_t)S_VOX);
        float4 c3 = *(const float4*)(lB + abase + 3 * (size_t)S_VOX);

        float dv[4];
        #pragma unroll
        for (int j = 0; j < 4; ++j) {
            float av[NCLS] = { ((const float*)&a0)[j], ((const float*)&a1)[j],
                               ((const float*)&a2)[j], ((const float*)&a3)[j] };
            float bv[NCLS] = { ((const float*)&c0)[j], ((const float*)&c1)[j],
                               ((const float*)&c2)[j], ((const float*)&c3)[j] };
            float maxA = fmaxf(fmaxf(av[0], av[1]), fmaxf(av[2], av[3]));
            float maxB = fmaxf(fmaxf(bv[0], bv[1]), fmaxf(bv[2], bv[3]));
            float eA[NCLS], eB[NCLS];
            float sA = 0.f, sB = 0.f;
            #pragma unroll
            for (int c = 0; c < NCLS; ++c) {
                eA[c] = __expf(av[c] - maxA); sA += eA[c];
                eB[c] = __expf(bv[c] - maxB); sB += eB[c];
            }
            float lseA = __logf(sA), lseB = __logf(sB);
            float rsA = 1.f / sA, rsB = 1.f / sB;
            float kl = 0.f;
            #pragma unroll
            for (int c = 0; c < NCLS; ++c) {
                float pA  = eA[c] * rsA;
                float pB  = eB[c] * rsB;
                float la  = av[c] - maxA - lseA;   // log pA
                float lb  = bv[c] - maxB - lseB;   // log pB
                float lM  = __logf(0.5f * (pA + pB) + EPS_F);
                kl += pA * (la - lM) + pB * (lb - lM);
            }
            dv[j] = 0.5f * kl;
        }

        // labels, then pack into low 2 mantissa bits of dis (<=3ulp perturb)
        unsigned lbls[4];
        #pragma unroll
        for (int j = 0; j < 4; ++j)
            lbls[j] = lab32[(size_t)(g + j) * lstride] & 3u;

        unsigned pw[4];
        #pragma unroll
        for (int j = 0; j < 4; ++j)
            pw[j] = (__float_as_uint(dv[j]) & ~3u) | lbls[j];
        *(uint4*)(disp + g) = make_uint4(pw[0], pw[1], pw[2], pw[3]);

        // per-class min/max on the EXACT dv
        #pragma unroll
        for (int j = 0; j < 4; ++j) {
            unsigned key = f2key(dv[j]);
            #pragma unroll
            for (int c = 0; c < NCLS; ++c) {
                if (lbls[j] == (unsigned)c) {
                    lmin[c] = min(lmin[c], key);
                    lmax[c] = max(lmax[c], key);
                }
            }
        }
    }

    // wave reduce (64 lanes)
    #pragma unroll
    for (int off = 32; off > 0; off >>= 1) {
        #pragma unroll
        for (int c = 0; c < NCLS; ++c) {
            unsigned om = (unsigned)__shfl_xor((int)lmin[c], off);
            unsigned oM = (unsigned)__shfl_xor((int)lmax[c], off);
            lmin[c] = min(lmin[c], om);
            lmax[c] = max(lmax[c], oM);
        }
    }
    if ((threadIdx.x & 63) == 0) {
        #pragma unroll
        for (int c = 0; c < NCLS; ++c) {
            atomicMin(&smin[c], lmin[c]);
            atomicMax(&smax[c], lmax[c]);
        }
    }
    __syncthreads();
    // NO global atomics: plain per-block partial store (contention-free).
    if (threadIdx.x < 8) {
        unsigned val = (threadIdx.x < NCLS) ? smin[threadIdx.x] : smax[threadIdx.x - NCLS];
        partials[(size_t)blockIdx.x * 8 + threadIdx.x] = val;
    }
}

// Reduce DIS_BLOCKS partial slots, then fold per-class stats into
// gamma = base[c] + mult[c] * dis.   1 block x 256 threads.
__global__ void __launch_bounds__(256)
k_stats(const unsigned* __restrict__ partials, const float* __restrict__ ranks,
        float* __restrict__ params) {
    __shared__ unsigned red[4][8];      // [wave][min0..3,max0..3]
    const int tid = threadIdx.x;

    unsigned mn[NCLS] = {0xFFFFFFFFu, 0xFFFFFFFFu, 0xFFFFFFFFu, 0xFFFFFFFFu};
    unsigned mx[NCLS] = {0u, 0u, 0u, 0u};
    // 1024 slots / 256 threads = 4 contiguous slots per thread
    #pragma unroll
    for (int s = 0; s < 4; ++s) {
        const unsigned* p = partials + ((size_t)tid * 4 + s) * 8;
        uint4 pmin = *(const uint4*)(p);
        uint4 pmax = *(const uint4*)(p + 4);
        mn[0] = min(mn[0], pmin.x); mn[1] = min(mn[1], pmin.y);
        mn[2] = min(mn[2], pmin.z); mn[3] = min(mn[3], pmin.w);
        mx[0] = max(mx[0], pmax.x); mx[1] = max(mx[1], pmax.y);
        mx[2] = max(mx[2], pmax.z); mx[3] = max(mx[3], pmax.w);
    }
    #pragma unroll
    for (int off = 32; off > 0; off >>= 1) {
        #pragma unroll
        for (int c = 0; c < NCLS; ++c) {
            unsigned om = (unsigned)__shfl_xor((int)mn[c], off);
            unsigned oM = (unsigned)__shfl_xor((int)mx[c], off);
            mn[c] = min(mn[c], om);
            mx[c] = max(mx[c], oM);
        }
    }
    if ((tid & 63) == 0) {
        const int w = tid >> 6;
        #pragma unroll
        for (int c = 0; c < NCLS; ++c) { red[w][c] = mn[c]; red[w][NCLS + c] = mx[c]; }
    }
    __syncthreads();
    if (tid < NCLS) {
        const int c = tid;
        unsigned kmin = 0xFFFFFFFFu, kmax = 0u;
        #pragma unroll
        for (int w = 0; w < 4; ++w) {
            kmin = min(kmin, red[w][c]);
            kmax = max(kmax, red[w][NCLS + c]);
        }
        bool present = (kmin != 0xFFFFFFFFu);
        float dmin = present ? key2f(kmin) : 0.0f;
        float dmax = present ? key2f(kmax) : LOG2_F;
        float inter = 1.0f - ranks[c] * (1.0f / (NCLS - 1));
        float base, mult;
        if (dmax > dmin) {
            float inv = 1.0f / (dmax - dmin + EPS_F);
            mult = inter * inv;
            base = 1.0f - mult * dmin;
        } else {
            mult = 0.0f;
            base = 1.0f + 0.5f * inter;
        }
        params[c] = base;
        params[NCLS + c] = mult;
    }
}

// Fused streaming scale + gamma materialization.
// out[e] = feat[e] * gamma(v);  gamma = base[lbl] + mult[lbl]*dis, computed
// inline from the packed disp word (cached).  Chunks on the f==0 plane also
// write gamma_map (uniform per-chunk branch).
// Block-adjacent x4 unroll, every instruction 64 lanes x 16B DENSE
// (stride-split R4 and thread-adjacent R5 both regressed — keep density).
__global__ void __launch_bounds__(256)
k_scale(const float* __restrict__ feat, const unsigned* __restrict__ disp,
        const float* __restrict__ params, float* __restrict__ gamma_out,
        float* __restrict__ out) {
    const float b0 = params[0], b1 = params[1], b2 = params[2], b3 = params[3];
    const float m0 = params[4], m1 = params[5], m2 = params[6], m3 = params[7];

    const size_t nchunk = FEAT_ELEMS / 4096;      // 16384 chunks of 4096 elems
    for (size_t cb = blockIdx.x; cb < nchunk; cb += gridDim.x) {
        const int f0 = (int)((cb >> 8) & 31);     // f-plane of this chunk
        const size_t e0 = (cb << 12) + ((size_t)threadIdx.x << 2);
        const size_t gb = ((cb >> 13) << 20) + ((cb << 12) & (size_t)(S_VOX - 1))
                          + ((size_t)threadIdx.x << 2);

        // feature loads first (HBM, longest latency)
        f32x4 x0 = __builtin_nontemporal_load((const f32x4*)(feat + e0));
        f32x4 x1 = __builtin_nontemporal_load((const f32x4*)(feat + e0 + 1024));
        f32x4 x2 = __builtin_nontemporal_load((const f32x4*)(feat + e0 + 2048));
        f32x4 x3 = __builtin_nontemporal_load((const f32x4*)(feat + e0 + 3072));

        f32x4 ga[4];
        #pragma unroll
        for (int u = 0; u < 4; ++u) {
            uint4 dp = *(const uint4*)(disp + gb + (size_t)u * 1024);
            const unsigned dw[4] = { dp.x, dp.y, dp.z, dp.w };
            #pragma unroll
            for (int j = 0; j < 4; ++j) {
                const unsigned lbl = dw[j] & 3u;
                const float d = __uint_as_float(dw[j]);
                const float bb = (lbl & 1u) ? ((lbl & 2u) ? b3 : b1)
                                            : ((lbl & 2u) ? b2 : b0);
                const float mm = (lbl & 1u) ? ((lbl & 2u) ? m3 : m1)
                                            : ((lbl & 2u) ? m2 : m0);
                ga[u][j] = fmaf(mm, d, bb);
            }
        }

        __builtin_nontemporal_store(x0 * ga[0], (f32x4*)(out + e0));
        __builtin_nontemporal_store(x1 * ga[1], (f32x4*)(out + e0 + 1024));
        __builtin_nontemporal_store(x2 * ga[2], (f32x4*)(out + e0 + 2048));
        __builtin_nontemporal_store(x3 * ga[3], (f32x4*)(out + e0 + 3072));

        if (f0 == 0) {  // this chunk's v-range owns the gamma_map write
            #pragma unroll
            for (int u = 0; u < 4; ++u)
                *(f32x4*)(gamma_out + gb + (size_t)u * 1024) = ga[u];
        }
    }
}

extern "C" void kernel_launch(void* const* d_in, const int* in_sizes, int n_in,
                              void* d_out, int out_size, void* d_ws, size_t ws_size,
                              hipStream_t stream) {
    const float*    feat  = (const float*)d_in[0];
    const float*    lA    = (const float*)d_in[1];
    const float*    lB    = (const float*)d_in[2];
    const unsigned* lab32 = (const unsigned*)d_in[3];
    const float*    ranks = (const float*)d_in[4];
    float* out = (float*)d_out;

    char* ws = (char*)d_ws;
    int*      flag     = (int*)(ws + 32);
    float*    params   = (float*)(ws + 64);
    unsigned* disp     = (unsigned*)(ws + 256);
    unsigned* partials = (unsigned*)(ws + 256 + (size_t)NVOX * 4);   // 32 KB

    float* gamma_out = out + (size_t)FEAT_ELEMS;

    k_prolog<<<1, 64, 0, stream>>>(lab32, flag);
    k_dis<<<DIS_BLOCKS, 256, 0, stream>>>(lA, lB, lab32, flag, disp, partials);
    k_stats<<<1, 256, 0, stream>>>(partials, ranks, params);
    k_scale<<<8192, 256, 0, stream>>>(feat, disp, params, gamma_out, out);
}

// Round 11
// 120.042 us; speedup vs baseline: 1.8171x; 1.0377x over previous
//
#include <hip/hip_runtime.h>
#include <hip/hip_bf16.h>

// Problem constants (fixed shapes): B=2, F=32, C=4, D=64, H=128, W=128
#define S_VOX  1048576          // D*H*W = 2^20
#define NVOX   2097152          // B * S_VOX
#define NCLS   4
#define NFEAT  32
#define FEAT_ELEMS 67108864     // B*F*S_VOX
#define EPS_F  1e-8f
#define LOG2_F 0.6931471805599453f
#define DIS_BLOCKS 2048

typedef float f32x4 __attribute__((ext_vector_type(4)));

// ---- monotonic float <-> orderable uint key ----
__device__ __forceinline__ unsigned f2key(float f) {
    unsigned u = __float_as_uint(f);
    return (u & 0x80000000u) ? ~u : (u | 0x80000000u);
}
__device__ __forceinline__ float key2f(unsigned k) {
    unsigned u = (k & 0x80000000u) ? (k & 0x7FFFFFFFu) : ~k;
    return __uint_as_float(u);
}

// ws layout (bytes):
//   64      : float    params[8]            (base[4], mult[4])
//   256     : unsigned disp[NVOX]           (8 MB: dis bits with label packed
//                                            into low 2 mantissa bits)
//   256+8MB : unsigned partials[DIS_BLOCKS*8]  (min[4],max[4] per block, 64 KB)

__global__ void __launch_bounds__(256)
k_dis(const float* __restrict__ lA, const float* __restrict__ lB,
      const unsigned* __restrict__ lab32,
      unsigned* __restrict__ disp, unsigned* __restrict__ partials) {
    __shared__ unsigned smin[NCLS], smax[NCLS];
    __shared__ int s_lstride;
    if (threadIdx.x < NCLS) { smin[threadIdx.x] = 0xFFFFFFFFu; smax[threadIdx.x] = 0u; }
    // fused prolog: wave 0 detects int64 vs int32 labels (odd 32-bit words of
    // the first 128 all zero while some even word nonzero => int64)
    if (threadIdx.x < 64) {
        unsigned even = lab32[2 * threadIdx.x];
        unsigned odd  = lab32[2 * threadIdx.x + 1];
        unsigned long long oddnz  = __ballot(odd  != 0u);
        unsigned long long evennz = __ballot(even != 0u);
        if (threadIdx.x == 0)
            s_lstride = (oddnz == 0ull && evennz != 0ull) ? 2 : 1;
    }
    __syncthreads();

    const int lstride = s_lstride;
    unsigned lmin[NCLS] = {0xFFFFFFFFu, 0xFFFFFFFFu, 0xFFFFFFFFu, 0xFFFFFFFFu};
    unsigned lmax[NCLS] = {0u, 0u, 0u, 0u};

    const int nquad = NVOX / 4;
    for (int q = blockIdx.x * blockDim.x + threadIdx.x; q < nquad;
         q += gridDim.x * blockDim.x) {
        const int g = q << 2;                 // base voxel index
        const int b = g >> 20;                // batch
        const int v = g & (S_VOX - 1);
        const size_t abase = ((size_t)b * NCLS) * S_VOX + v;

        float4 a0 = *(const float4*)(lA + abase);
        float4 a1 = *(const float4*)(lA + abase + S_VOX);
        float4 a2 = *(const float4*)(lA + abase + 2 * (size_t)S_VOX);
        float4 a3 = *(const float4*)(lA + abase + 3 * (size_t)S_VOX);
        float4 c0 = *(const float4*)(lB + abase);
        float4 c1 = *(const float4*)(lB + abase + S_VOX);
        float4 c2 = *(const float4*)(lB + abase + 2 * (size_t)S_VOX);
        float4 c3 = *(const float4*)(lB + abase + 3 * (size_t)S_VOX);

        float dv[4];
        #pragma unroll
        for (int j = 0; j < 4; ++j) {
            float av[NCLS] = { ((const float*)&a0)[j], ((const float*)&a1)[j],
                               ((const float*)&a2)[j], ((const float*)&a3)[j] };
            float bv[NCLS] = { ((const float*)&c0)[j], ((const float*)&c1)[j],
                               ((const float*)&c2)[j], ((const float*)&c3)[j] };
            float maxA = fmaxf(fmaxf(av[0], av[1]), fmaxf(av[2], av[3]));
            float maxB = fmaxf(fmaxf(bv[0], bv[1]), fmaxf(bv[2], bv[3]));
            float eA[NCLS], eB[NCLS];
            float sA = 0.f, sB = 0.f;
            #pragma unroll
            for (int c = 0; c < NCLS; ++c) {
                eA[c] = __expf(av[c] - maxA); sA += eA[c];
                eB[c] = __expf(bv[c] - maxB); sB += eB[c];
            }
            float lseA = __logf(sA), lseB = __logf(sB);
            float rsA = 1.f / sA, rsB = 1.f / sB;
            float kl = 0.f;
            #pragma unroll
            for (int c = 0; c < NCLS; ++c) {
                float pA  = eA[c] * rsA;
                float pB  = eB[c] * rsB;
                float la  = av[c] - maxA - lseA;   // log pA
                float lb  = bv[c] - maxB - lseB;   // log pB
                float lM  = __logf(0.5f * (pA + pB) + EPS_F);
                kl += pA * (la - lM) + pB * (lb - lM);
            }
            dv[j] = 0.5f * kl;
        }

        // vectorized label loads (dense 1KB per instruction)
        unsigned lbls[4];
        if (lstride == 2) {
            uint4 L0 = *(const uint4*)(lab32 + 2 * (size_t)g);
            uint4 L1 = *(const uint4*)(lab32 + 2 * (size_t)g + 4);
            lbls[0] = L0.x & 3u; lbls[1] = L0.z & 3u;
            lbls[2] = L1.x & 3u; lbls[3] = L1.z & 3u;
        } else {
            uint4 L = *(const uint4*)(lab32 + (size_t)g);
            lbls[0] = L.x & 3u; lbls[1] = L.y & 3u;
            lbls[2] = L.z & 3u; lbls[3] = L.w & 3u;
        }

        // pack label into low 2 mantissa bits of dis (<=3ulp perturb)
        unsigned pw[4];
        #pragma unroll
        for (int j = 0; j < 4; ++j)
            pw[j] = (__float_as_uint(dv[j]) & ~3u) | lbls[j];
        *(uint4*)(disp + g) = make_uint4(pw[0], pw[1], pw[2], pw[3]);

        // per-class min/max on the EXACT dv
        #pragma unroll
        for (int j = 0; j < 4; ++j) {
            unsigned key = f2key(dv[j]);
            #pragma unroll
            for (int c = 0; c < NCLS; ++c) {
                if (lbls[j] == (unsigned)c) {
                    lmin[c] = min(lmin[c], key);
                    lmax[c] = max(lmax[c], key);
                }
            }
        }
    }

    // wave reduce (64 lanes)
    #pragma unroll
    for (int off = 32; off > 0; off >>= 1) {
        #pragma unroll
        for (int c = 0; c < NCLS; ++c) {
            unsigned om = (unsigned)__shfl_xor((int)lmin[c], off);
            unsigned oM = (unsigned)__shfl_xor((int)lmax[c], off);
            lmin[c] = min(lmin[c], om);
            lmax[c] = max(lmax[c], oM);
        }
    }
    if ((threadIdx.x & 63) == 0) {
        #pragma unroll
        for (int c = 0; c < NCLS; ++c) {
            atomicMin(&smin[c], lmin[c]);
            atomicMax(&smax[c], lmax[c]);
        }
    }
    __syncthreads();
    // NO global atomics: plain per-block partial store (contention-free).
    if (threadIdx.x < 8) {
        unsigned val = (threadIdx.x < NCLS) ? smin[threadIdx.x] : smax[threadIdx.x - NCLS];
        partials[(size_t)blockIdx.x * 8 + threadIdx.x] = val;
    }
}

// Reduce DIS_BLOCKS partial slots, then fold per-class stats into
// gamma = base[c] + mult[c] * dis.   1 block x 256 threads.
__global__ void __launch_bounds__(256)
k_stats(const unsigned* __restrict__ partials, const float* __restrict__ ranks,
        float* __restrict__ params) {
    __shared__ unsigned red[4][8];      // [wave][min0..3,max0..3]
    const int tid = threadIdx.x;

    unsigned mn[NCLS] = {0xFFFFFFFFu, 0xFFFFFFFFu, 0xFFFFFFFFu, 0xFFFFFFFFu};
    unsigned mx[NCLS] = {0u, 0u, 0u, 0u};
    // 2048 slots / 256 threads = 8 contiguous slots per thread
    #pragma unroll
    for (int s = 0; s < 8; ++s) {
        const unsigned* p = partials + ((size_t)tid * 8 + s) * 8;
        uint4 pmin = *(const uint4*)(p);
        uint4 pmax = *(const uint4*)(p + 4);
        mn[0] = min(mn[0], pmin.x); mn[1] = min(mn[1], pmin.y);
        mn[2] = min(mn[2], pmin.z); mn[3] = min(mn[3], pmin.w);
        mx[0] = max(mx[0], pmax.x); mx[1] = max(mx[1], pmax.y);
        mx[2] = max(mx[2], pmax.z); mx[3] = max(mx[3], pmax.w);
    }
    #pragma unroll
    for (int off = 32; off > 0; off >>= 1) {
        #pragma unroll
        for (int c = 0; c < NCLS; ++c) {
            unsigned om = (unsigned)__shfl_xor((int)mn[c], off);
            unsigned oM = (unsigned)__shfl_xor((int)mx[c], off);
            mn[c] = min(mn[c], om);
            mx[c] = max(mx[c], oM);
        }
    }
    if ((tid & 63) == 0) {
        const int w = tid >> 6;
        #pragma unroll
        for (int c = 0; c < NCLS; ++c) { red[w][c] = mn[c]; red[w][NCLS + c] = mx[c]; }
    }
    __syncthreads();
    if (tid < NCLS) {
        const int c = tid;
        unsigned kmin = 0xFFFFFFFFu, kmax = 0u;
        #pragma unroll
        for (int w = 0; w < 4; ++w) {
            kmin = min(kmin, red[w][c]);
            kmax = max(kmax, red[w][NCLS + c]);
        }
        bool present = (kmin != 0xFFFFFFFFu);
        float dmin = present ? key2f(kmin) : 0.0f;
        float dmax = present ? key2f(kmax) : LOG2_F;
        float inter = 1.0f - ranks[c] * (1.0f / (NCLS - 1));
        float base, mult;
        if (dmax > dmin) {
            float inv = 1.0f / (dmax - dmin + EPS_F);
            mult = inter * inv;
            base = 1.0f - mult * dmin;
        } else {
            mult = 0.0f;
            base = 1.0f + 0.5f * inter;
        }
        params[c] = base;
        params[NCLS + c] = mult;
    }
}

// Fused streaming scale + gamma materialization.
// out[e] = feat[e] * gamma(v);  gamma = base[lbl] + mult[lbl]*dis, computed
// inline from the packed disp word (cached).  Chunks on the f==0 plane also
// write gamma_map (uniform per-chunk branch).
// Block-adjacent x4 unroll, every instruction 64 lanes x 16B DENSE
// (stride-split R4 and thread-adjacent R5 both regressed — keep density).
__global__ void __launch_bounds__(256)
k_scale(const float* __restrict__ feat, const unsigned* __restrict__ disp,
        const float* __restrict__ params, float* __restrict__ gamma_out,
        float* __restrict__ out) {
    const float b0 = params[0], b1 = params[1], b2 = params[2], b3 = params[3];
    const float m0 = params[4], m1 = params[5], m2 = params[6], m3 = params[7];

    const size_t nchunk = FEAT_ELEMS / 4096;      // 16384 chunks of 4096 elems
    for (size_t cb = blockIdx.x; cb < nchunk; cb += gridDim.x) {
        const int f0 = (int)((cb >> 8) & 31);     // f-plane of this chunk
        const size_t e0 = (cb << 12) + ((size_t)threadIdx.x << 2);
        const size_t gb = ((cb >> 13) << 20) + ((cb << 12) & (size_t)(S_VOX - 1))
                          + ((size_t)threadIdx.x << 2);

        // feature loads first (HBM, longest latency)
        f32x4 x0 = __builtin_nontemporal_load((const f32x4*)(feat + e0));
        f32x4 x1 = __builtin_nontemporal_load((const f32x4*)(feat + e0 + 1024));
        f32x4 x2 = __builtin_nontemporal_load((const f32x4*)(feat + e0 + 2048));
        f32x4 x3 = __builtin_nontemporal_load((const f32x4*)(feat + e0 + 3072));

        f32x4 ga[4];
        #pragma unroll
        for (int u = 0; u < 4; ++u) {
            uint4 dp = *(const uint4*)(disp + gb + (size_t)u * 1024);
            const unsigned dw[4] = { dp.x, dp.y, dp.z, dp.w };
            #pragma unroll
            for (int j = 0; j < 4; ++j) {
                const unsigned lbl = dw[j] & 3u;
                const float d = __uint_as_float(dw[j]);
                const float bb = (lbl & 1u) ? ((lbl & 2u) ? b3 : b1)
                                            : ((lbl & 2u) ? b2 : b0);
                const float mm = (lbl & 1u) ? ((lbl & 2u) ? m3 : m1)
                                            : ((lbl & 2u) ? m2 : m0);
                ga[u][j] = fmaf(mm, d, bb);
            }
        }

        __builtin_nontemporal_store(x0 * ga[0], (f32x4*)(out + e0));
        __builtin_nontemporal_store(x1 * ga[1], (f32x4*)(out + e0 + 1024));
        __builtin_nontemporal_store(x2 * ga[2], (f32x4*)(out + e0 + 2048));
        __builtin_nontemporal_store(x3 * ga[3], (f32x4*)(out + e0 + 3072));

        if (f0 == 0) {  // this chunk's v-range owns the gamma_map write
            #pragma unroll
            for (int u = 0; u < 4; ++u)
                *(f32x4*)(gamma_out + gb + (size_t)u * 1024) = ga[u];
        }
    }
}

extern "C" void kernel_launch(void* const* d_in, const int* in_sizes, int n_in,
                              void* d_out, int out_size, void* d_ws, size_t ws_size,
                              hipStream_t stream) {
    const float*    feat  = (const float*)d_in[0];
    const float*    lA    = (const float*)d_in[1];
    const float*    lB    = (const float*)d_in[2];
    const unsigned* lab32 = (const unsigned*)d_in[3];
    const float*    ranks = (const float*)d_in[4];
    float* out = (float*)d_out;

    char* ws = (char*)d_ws;
    float*    params   = (float*)(ws + 64);
    unsigned* disp     = (unsigned*)(ws + 256);
    unsigned* partials = (unsigned*)(ws + 256 + (size_t)NVOX * 4);   // 64 KB

    float* gamma_out = out + (size_t)FEAT_ELEMS;

    k_dis<<<DIS_BLOCKS, 256, 0, stream>>>(lA, lB, lab32, disp, partials);
    k_stats<<<1, 256, 0, stream>>>(partials, ranks, params);
    k_scale<<<8192, 256, 0, stream>>>(feat, disp, params, gamma_out, out);
}